// Round 7
// baseline (1174.566 us; speedup 1.0000x reference)
//
#include <hip/hip_runtime.h>
#include <hip/hip_bf16.h>
#include <math.h>

typedef __hip_bfloat16 bf16;
typedef __attribute__((ext_vector_type(8))) short bf16x8;
typedef __attribute__((ext_vector_type(4))) short bf16x4;
typedef __attribute__((ext_vector_type(4))) float f32x4;

#define EPI_NONE 0
#define EPI_BIAS_BF16 1
#define EPI_BIAS_GELU_BF16 2

#define CLOG 0.18033688f   // 0.125 * log2(e) — attention scale folded into exp2

__device__ __forceinline__ void gload16(const void* g, void* l) {
  __builtin_amdgcn_global_load_lds((const __attribute__((address_space(1))) void*)g,
                                   (__attribute__((address_space(3))) void*)l, 16, 0, 0);
}

__device__ __forceinline__ float gelu_tanh(float x) {
  const float c = 0.7978845608028654f;
  float t = tanhf(c * (x + 0.044715f * x * x * x));
  return 0.5f * x * (1.0f + t);
}

__device__ __forceinline__ short bf16bits(float x) {
  bf16 h = __float2bfloat16(x);
  return *reinterpret_cast<const short*>(&h);
}

// C = A @ Bt^T (+bias, epilogue). A:[M][K] bf16 lda, Bt:[N][K] bf16 ldb.
// z: generic slab offsets (split-K). 256 thr = 4 waves, wave tile (BM/2)x(BN/2).
// global_load_lds width-16 staging; BK=64 halves barrier count vs BK=32.
template<int BM, int BN, int BK, int EPI, typename CT>
__global__ __launch_bounds__(256) void gemm_bt(
    const bf16* __restrict__ A, long sAz, int lda,
    const bf16* __restrict__ Bt, long sBz, int ldb,
    CT* __restrict__ C, long sCz, int ldc,
    const float* __restrict__ bias,
    int K, float scale)
{
  constexpr int WM = BM / 2, WN = BN / 2;
  constexpr int MI = WM / 16, NJ = WN / 16;
  constexpr int NA = (BM * BK * 2) / 4096;
  constexpr int NB = (BN * BK * 2) / 4096;
  constexpr int ROWB = BK * 2;          // bytes per LDS row
  __shared__ __align__(16) bf16 As[BM * BK];
  __shared__ __align__(16) bf16 Bs[BN * BK];
  const int t = threadIdx.x;
  const int lane = t & 63, w = t >> 6;
  const int wm = (w >> 1) * WM, wn = (w & 1) * WN;
  const int quad = lane >> 4, r16 = lane & 15;
  const long z = blockIdx.z;
  const bf16* Ab = A + z * sAz + (long)blockIdx.y * BM * lda;
  const bf16* Bb = Bt + z * sBz + (long)blockIdx.x * BN * ldb;

  f32x4 acc[MI][NJ];
  #pragma unroll
  for (int i = 0; i < MI; ++i)
    #pragma unroll
    for (int j = 0; j < NJ; ++j)
      acc[i][j] = (f32x4){0.f, 0.f, 0.f, 0.f};

  for (int k0 = 0; k0 < K; k0 += BK) {
    __syncthreads();
    #pragma unroll
    for (int s = 0; s < NA; ++s) {
      int Lb = s * 4096 + t * 16;
      int row = Lb / ROWB, colb = Lb % ROWB;
      gload16((const char*)Ab + (long)row * (lda * 2) + k0 * 2 + colb, (char*)As + Lb);
    }
    #pragma unroll
    for (int s = 0; s < NB; ++s) {
      int Lb = s * 4096 + t * 16;
      int row = Lb / ROWB, colb = Lb % ROWB;
      gload16((const char*)Bb + (long)row * (ldb * 2) + k0 * 2 + colb, (char*)Bs + Lb);
    }
    __syncthreads();   // vmcnt(0) drain before barrier (compiler-inserted)

    #pragma unroll
    for (int kk = 0; kk < BK / 32; ++kk) {
      bf16x8 af[MI], bfv[NJ];
      #pragma unroll
      for (int i = 0; i < MI; ++i)
        af[i] = *(const bf16x8*)&As[(wm + i * 16 + r16) * BK + kk * 32 + quad * 8];
      #pragma unroll
      for (int j = 0; j < NJ; ++j)
        bfv[j] = *(const bf16x8*)&Bs[(wn + j * 16 + r16) * BK + kk * 32 + quad * 8];
      #pragma unroll
      for (int i = 0; i < MI; ++i)
        #pragma unroll
        for (int j = 0; j < NJ; ++j)
          acc[i][j] = __builtin_amdgcn_mfma_f32_16x16x32_bf16(af[i], bfv[j], acc[i][j], 0, 0, 0);
    }
  }

  CT* Cb = C + z * sCz;
  #pragma unroll
  for (int i = 0; i < MI; ++i) {
    #pragma unroll
    for (int j = 0; j < NJ; ++j) {
      int col = blockIdx.x * BN + wn + j * 16 + r16;
      float bvv = 0.f;
      if constexpr (EPI == EPI_BIAS_BF16 || EPI == EPI_BIAS_GELU_BF16)
        bvv = bias[col];
      #pragma unroll
      for (int r = 0; r < 4; ++r) {
        long row = (long)blockIdx.y * BM + wm + i * 16 + quad * 4 + r;
        float val = acc[i][j][r] * scale + bvv;
        if constexpr (EPI == EPI_BIAS_GELU_BF16) val = gelu_tanh(val);
        if constexpr (sizeof(CT) == 2)
          Cb[row * (long)ldc + col] = __float2bfloat16(val);
        else
          Cb[row * (long)ldc + col] = val;
      }
    }
  }
}

// Key-split flash attention: block = (64-row Q tile, head, key-split).
// kts = K-tiles (of 64 keys) per split; grid.z = nsplit. Round-2-verified
// loop body (LDS-staged K/V + one-tile-ahead register prefetch, 2 barriers);
// Q fragments direct from global (verified r3/r5) — drops Qs LDS, 36.8->28.7 KB,
// so 5 blocks/CU fit and a 2048-block grid (nsplit=4) lifts occupancy ~34->~60%.
// Writes unnormalized fp32 O into Osp slab [split][S][1024], (m,l) into ml.
__global__ __launch_bounds__(256) void flash_attn(
    const bf16* __restrict__ qkv, const bf16* __restrict__ vT,
    float* __restrict__ Osp, float2* __restrict__ ml, int kts)
{
  constexpr int SEQ = 2048, LDP = 72, LDPP = 80;
  __shared__ __align__(16) bf16 Ks[64 * LDP];
  __shared__ __align__(16) bf16 VTs[64 * LDP];
  __shared__ __align__(16) bf16 Ps[64 * LDPP];

  const int t = threadIdx.x;
  const int lane = t & 63, w = t >> 6;
  const int quad = lane >> 4, r16 = lane & 15;
  const int wq0 = w * 16;
  const int s0 = blockIdx.x * 64;
  const int h = blockIdx.y;
  const int split = blockIdx.z;
  const int kt0 = split * kts, ktN = kt0 + kts;

  // Q fragments direct from global: row s0+wq0+r16, col h*64 + kk*32 + quad*8
  bf16x8 af_q[2];
  {
    const bf16* qp = qkv + (long)(s0 + wq0 + r16) * 3072 + h * 64 + quad * 8;
    af_q[0] = *(const bf16x8*)(qp);
    af_q[1] = *(const bf16x8*)(qp + 32);
  }

  const bf16* kp[2]; const bf16* vp[2];
  int krow[2], kcolb[2];
  #pragma unroll
  for (int s = 0; s < 2; ++s) {
    int Lb = s * 4096 + t * 16;
    krow[s] = Lb >> 7; kcolb[s] = Lb & 127;
    kp[s] = qkv + 1024 + (long)h * 64 + (long)krow[s] * 3072 + (kcolb[s] >> 1);
    vp[s] = vT + (long)(h * 64 + krow[s]) * SEQ + (kcolb[s] >> 1);
  }

  int4 rk[2], rv[2];
  #pragma unroll
  for (int s = 0; s < 2; ++s) {
    rk[s] = *(const int4*)(kp[s] + (long)kt0 * 64 * 3072);
    rv[s] = *(const int4*)(vp[s] + (long)kt0 * 64);
  }

  f32x4 O[4];
  float m_s = -1e30f, l_s = 0.f;   // per-lane: running (m,l) of q-row r16 (exp2/C-scaled)
  #pragma unroll
  for (int jd = 0; jd < 4; ++jd) O[jd] = (f32x4){0.f, 0.f, 0.f, 0.f};

  for (int kt = kt0; kt < ktN; ++kt) {
    __syncthreads();
    #pragma unroll
    for (int s = 0; s < 2; ++s) {
      *(int4*)((char*)Ks + (krow[s] * LDP * 2) + kcolb[s]) = rk[s];
      *(int4*)((char*)VTs + (krow[s] * LDP * 2) + kcolb[s]) = rv[s];
    }
    __syncthreads();

    if (kt + 1 < ktN) {
      long k0n = (long)(kt + 1) * 64;
      #pragma unroll
      for (int s = 0; s < 2; ++s) {
        rk[s] = *(const int4*)(kp[s] + k0n * 3072);
        rv[s] = *(const int4*)(vp[s] + k0n);
      }
    }

    // S^T = K @ Q^T (raw; scale folded into exp2 constant).
    // sc[jb] reg r = S[qrow=r16][key = jb*16 + quad*4 + r]
    f32x4 sc[4];
    #pragma unroll
    for (int j = 0; j < 4; ++j) sc[j] = (f32x4){0.f, 0.f, 0.f, 0.f};
    #pragma unroll
    for (int kk = 0; kk < 2; ++kk) {
      bf16x8 bk_f[4];
      #pragma unroll
      for (int j = 0; j < 4; ++j)
        bk_f[j] = *(const bf16x8*)&Ks[(j * 16 + r16) * LDP + kk * 32 + quad * 8];
      #pragma unroll
      for (int j = 0; j < 4; ++j)
        sc[j] = __builtin_amdgcn_mfma_f32_16x16x32_bf16(bk_f[j], af_q[kk], sc[j], 0, 0, 0);
    }

    // lane-local online softmax for q-row r16: 16 in-lane keys + quad reduce
    float mj[4];
    #pragma unroll
    for (int j = 0; j < 4; ++j)
      mj[j] = fmaxf(fmaxf(sc[j][0], sc[j][1]), fmaxf(sc[j][2], sc[j][3]));
    float mx = fmaxf(fmaxf(mj[0], mj[1]), fmaxf(mj[2], mj[3]));
    mx = fmaxf(mx, __shfl_xor(mx, 16));
    mx = fmaxf(mx, __shfl_xor(mx, 32));
    float m_new = fmaxf(m_s, mx * CLOG);
    float alpha = exp2f(m_s - m_new);
    m_s = m_new;
    float p[4][4], sj[4];
    #pragma unroll
    for (int j = 0; j < 4; ++j) {
      #pragma unroll
      for (int r = 0; r < 4; ++r)
        p[j][r] = exp2f(fmaf(sc[j][r], CLOG, -m_new));
      sj[j] = (p[j][0] + p[j][1]) + (p[j][2] + p[j][3]);
    }
    float rs = (sj[0] + sj[1]) + (sj[2] + sj[3]);
    rs += __shfl_xor(rs, 16);
    rs += __shfl_xor(rs, 32);
    l_s = l_s * alpha + rs;

    // O rows are quad*4+r; their alpha lives at lane (*, r16'=quad*4+r)
    float ar[4];
    #pragma unroll
    for (int r = 0; r < 4; ++r)
      ar[r] = __shfl(alpha, quad * 20 + r);   // src = quad*16 + (quad*4+r)
    #pragma unroll
    for (int jd = 0; jd < 4; ++jd)
      #pragma unroll
      for (int r = 0; r < 4; ++r)
        O[jd][r] *= ar[r];

    // pack P row r16 -> LDS as 4x b64 (wave-private rows; same-wave DS ordering)
    {
      bf16* pr = &Ps[(wq0 + r16) * LDPP + quad * 4];
      #pragma unroll
      for (int j = 0; j < 4; ++j) {
        bf16x4 pk;
        #pragma unroll
        for (int r = 0; r < 4; ++r)
          pk[r] = bf16bits(p[j][r]);
        *(bf16x4*)(pr + j * 16) = pk;
      }
    }

    // O += P @ V via VT[d][key]
    #pragma unroll
    for (int kk = 0; kk < 2; ++kk) {
      bf16x8 af_p, bv_f[4];
      af_p = *(const bf16x8*)&Ps[(wq0 + r16) * LDPP + kk * 32 + quad * 8];
      #pragma unroll
      for (int jd = 0; jd < 4; ++jd)
        bv_f[jd] = *(const bf16x8*)&VTs[(jd * 16 + r16) * LDP + kk * 32 + quad * 8];
      #pragma unroll
      for (int jd = 0; jd < 4; ++jd)
        O[jd] = __builtin_amdgcn_mfma_f32_16x16x32_bf16(af_p, bv_f[jd], O[jd], 0, 0, 0);
    }
  }

  // epilogue: unnormalized fp32 O + (m,l)
  float* Ob = Osp + (long)split * SEQ * 1024;
  #pragma unroll
  for (int r = 0; r < 4; ++r) {
    long row = s0 + wq0 + quad * 4 + r;
    #pragma unroll
    for (int jd = 0; jd < 4; ++jd)
      Ob[row * 1024 + h * 64 + jd * 16 + r16] = O[jd][r];
  }
  if (quad == 0)
    ml[((long)(split * 16 + h)) * SEQ + (s0 + wq0 + r16)] = make_float2(m_s, l_s);
}

// merge nsplit key-splits -> ctx bf16 (ml re-read is tiny & L2-hot; avoids
// runtime-indexed register arrays going to scratch)
__global__ __launch_bounds__(256) void attn_combine(
    const float* __restrict__ Osp, const float2* __restrict__ ml,
    bf16* __restrict__ ctx, int nsplit)
{
  constexpr long SD = 2048L * 1024L;
  const int s = blockIdx.x;
  const int t = threadIdx.x;
  #pragma unroll
  for (int i = 0; i < 4; ++i) {
    int c = t + i * 256;
    int h = c >> 6;
    float mC = -1e30f;
    for (int sp = 0; sp < nsplit; ++sp)
      mC = fmaxf(mC, ml[(long)(sp * 16 + h) * 2048 + s].x);
    float denom = 0.f, num = 0.f;
    for (int sp = 0; sp < nsplit; ++sp) {
      float2 a = ml[(long)(sp * 16 + h) * 2048 + s];
      float wv = exp2f(a.x - mC);
      denom += a.y * wv;
      num += Osp[sp * SD + (long)s * 1024 + c] * wv;
    }
    ctx[(long)s * 1024 + c] = __float2bfloat16(num / denom);
  }
}

// fp32 weight [R][C] -> bf16 transposed [C][R]
__global__ __launch_bounds__(256) void transpose_cast(
    const float* __restrict__ in, bf16* __restrict__ out, int R, int C)
{
  __shared__ bf16 tile[32][33];
  const int tx = threadIdx.x, ty = threadIdx.y;
  const int r0 = blockIdx.y * 32, c0 = blockIdx.x * 32;
  #pragma unroll
  for (int d = 0; d < 32; d += 8)
    tile[ty + d][tx] = __float2bfloat16(in[(long)(r0 + ty + d) * C + c0 + tx]);
  __syncthreads();
  #pragma unroll
  for (int d = 0; d < 32; d += 8)
    out[(long)(c0 + ty + d) * R + r0 + tx] = tile[tx][ty + d];
}

// batched variant: z selects one of three same-shape fp32 [R][C] weights,
// output slabs out + z*R*C. Saves 2 kernel launches per layer for QKV.
__global__ __launch_bounds__(256) void transpose_cast3(
    const float* __restrict__ w0, const float* __restrict__ w1p,
    const float* __restrict__ w2p, bf16* __restrict__ out, int R, int C)
{
  __shared__ bf16 tile[32][33];
  const float* in = (blockIdx.z == 0) ? w0 : (blockIdx.z == 1) ? w1p : w2p;
  bf16* o = out + (long)blockIdx.z * R * C;
  const int tx = threadIdx.x, ty = threadIdx.y;
  const int r0 = blockIdx.y * 32, c0 = blockIdx.x * 32;
  #pragma unroll
  for (int d = 0; d < 32; d += 8)
    tile[ty + d][tx] = __float2bfloat16(in[(long)(r0 + ty + d) * C + c0 + tx]);
  __syncthreads();
  #pragma unroll
  for (int d = 0; d < 32; d += 8)
    o[(long)(c0 + ty + d) * R + r0 + tx] = tile[tx][ty + d];
}

// bf16 [R][C] (row stride ldin) -> bf16 transposed [C][R]
__global__ __launch_bounds__(256) void transpose_bf16(
    const bf16* __restrict__ in, bf16* __restrict__ out, int R, int C, int ldin)
{
  __shared__ bf16 tile[32][33];
  const int tx = threadIdx.x, ty = threadIdx.y;
  const int r0 = blockIdx.y * 32, c0 = blockIdx.x * 32;
  #pragma unroll
  for (int d = 0; d < 32; d += 8)
    tile[ty + d][tx] = in[(long)(r0 + ty + d) * ldin + c0 + tx];
  __syncthreads();
  #pragma unroll
  for (int d = 0; d < 32; d += 8)
    out[(long)(c0 + ty + d) * R + r0 + tx] = tile[tx][ty + d];
}

__device__ __forceinline__ float blk_sum(float v, float* sh) {
  #pragma unroll
  for (int o = 32; o > 0; o >>= 1) v += __shfl_down(v, o);
  __syncthreads();
  if ((threadIdx.x & 63) == 0) sh[threadIdx.x >> 6] = v;
  __syncthreads();
  return sh[0] + sh[1] + sh[2] + sh[3];
}

// X = LN(X + d0 + d1 + bias)*g + b, writes bf16 copy to xb.
__global__ __launch_bounds__(256) void ln_residual2(
    float* __restrict__ X, const float* __restrict__ d0, const float* __restrict__ d1,
    const float* __restrict__ bias,
    const float* __restrict__ g, const float* __restrict__ b,
    bf16* __restrict__ xb)
{
  __shared__ float sh[4];
  const int t = threadIdx.x;
  const long base = (long)blockIdx.x * 1024;
  float v[4]; float s = 0.f;
  #pragma unroll
  for (int i = 0; i < 4; ++i) {
    int c = t + i * 256;
    float val = X[base + c] + d0[base + c] + d1[base + c] + bias[c];
    v[i] = val; s += val;
  }
  s = blk_sum(s, sh);
  const float mu = s * (1.f / 1024.f);
  float s2 = 0.f;
  #pragma unroll
  for (int i = 0; i < 4; ++i) { float d = v[i] - mu; s2 += d * d; }
  s2 = blk_sum(s2, sh);
  const float rs = rsqrtf(s2 * (1.f / 1024.f) + 1e-5f);
  #pragma unroll
  for (int i = 0; i < 4; ++i) {
    int c = t + i * 256;
    float o = (v[i] - mu) * rs * g[c] + b[c];
    X[base + c] = o;
    xb[base + c] = __float2bfloat16(o);
  }
}

__global__ __launch_bounds__(256) void init_x(
    const float* __restrict__ xin, float* __restrict__ X, bf16* __restrict__ xb, int n)
{
  for (int i = blockIdx.x * 256 + threadIdx.x; i < n; i += gridDim.x * 256) {
    float v = xin[i];
    X[i] = v;
    xb[i] = __float2bfloat16(v);
  }
}

__global__ __launch_bounds__(256) void copy_out(
    const float* __restrict__ X, float* __restrict__ out, int n)
{
  for (int i = blockIdx.x * 256 + threadIdx.x; i < n; i += gridDim.x * 256)
    out[i] = X[i];
}

// bias3[l][j][c] = {bq,bk,bv}[l][c]
__global__ __launch_bounds__(256) void concat_bias(
    const float* __restrict__ bq, const float* __restrict__ bk,
    const float* __restrict__ bv, float* __restrict__ out, int n)
{
  for (int i = blockIdx.x * 256 + threadIdx.x; i < n; i += gridDim.x * 256) {
    int l = i / 3072, r = i % 3072;
    int j = r / 1024, c = r % 1024;
    const float* src = (j == 0) ? bq : (j == 1) ? bk : bv;
    out[i] = src[l * 1024 + c];
  }
}

extern "C" void kernel_launch(void* const* d_in, const int* in_sizes, int n_in,
                              void* d_out, int out_size, void* d_ws, size_t ws_size,
                              hipStream_t stream) {
  constexpr int S = 2048, D = 1024, F = 4096, L = 4;
  const float* xin = (const float*)d_in[0];
  const float* wq = (const float*)d_in[1];
  const float* bq = (const float*)d_in[2];
  const float* wk = (const float*)d_in[3];
  const float* bk = (const float*)d_in[4];
  const float* wv = (const float*)d_in[5];
  const float* bvp = (const float*)d_in[6];
  const float* wo = (const float*)d_in[7];
  const float* bo = (const float*)d_in[8];
  const float* w1 = (const float*)d_in[9];
  const float* b1 = (const float*)d_in[10];
  const float* w2 = (const float*)d_in[11];
  const float* b2 = (const float*)d_in[12];
  const float* ln1g = (const float*)d_in[13];
  const float* ln1b = (const float*)d_in[14];
  const float* ln2g = (const float*)d_in[15];
  const float* ln2b = (const float*)d_in[16];

  // nsplit=4 needs ~73 MB of workspace (4 fp32 O-split slabs); fall back to 2.
  const int nsplit = (ws_size >= 78u * 1024 * 1024) ? 4 : 2;
  const int kts = 32 / nsplit;   // K-tiles (64 keys each) per split

  char* p = (char*)d_ws;
  float* X    = (float*)p; p += (long)S * D * 4;            // 8 MB
  float* tmpf = (float*)p; p += (long)nsplit * S * D * 4;   // 16/32 MB (split-K / O-split slabs)
  bf16* xb    = (bf16*)p;  p += (long)S * D * 2;            // 4 MB
  bf16* qkv   = (bf16*)p;                                   // 12 MB
  bf16* hb    = (bf16*)p;  p += (long)S * 3 * D * 2;        // hb overlays qkv..ctx
  bf16* ctx   = (bf16*)p;  p += (long)S * D * 2;            // 4 MB
  bf16* vT    = (bf16*)p;  p += (long)S * D * 2;            // 4 MB  [H*64][S]
  bf16* wT    = (bf16*)p;  p += (long)F * D * 2;            // 8 MB
  float* bias3= (float*)p; p += (long)L * 3 * D * 4;        // 48 KB
  float2* ml  = (float2*)p; p += (long)nsplit * 16 * S * 8; // (m,l) per split/head/row

  init_x<<<2048, 256, 0, stream>>>(xin, X, xb, S * D);
  concat_bias<<<48, 256, 0, stream>>>(bq, bk, bvp, bias3, L * 3 * D);

  for (int l = 0; l < L; ++l) {
    // fused QKV: one batched transpose launch + balanced 128x64 GEMM (3 blocks/CU)
    transpose_cast3<<<dim3(D / 32, D / 32, 3), dim3(32, 8), 0, stream>>>(
        wq + (long)l * D * D, wk + (long)l * D * D, wv + (long)l * D * D, wT, D, D);
    gemm_bt<128, 64, 64, EPI_BIAS_BF16, bf16><<<dim3(3 * D / 64, S / 128, 1), 256, 0, stream>>>(
        xb, 0L, D, wT, 0L, D, qkv, 0L, 3 * D, bias3 + l * 3 * D, D, 1.f);

    // vT[h*64+d][s]
    transpose_bf16<<<dim3(D / 32, S / 32), dim3(32, 8), 0, stream>>>(qkv + 2 * D, vT, S, D, 3 * D);

    // key-split flash + combine
    flash_attn<<<dim3(S / 64, 16, nsplit), 256, 0, stream>>>(qkv, vT, tmpf, ml, kts);
    attn_combine<<<S, 256, 0, stream>>>(tmpf, ml, ctx, nsplit);

    // attn-out, split-K 2 -> fp32 slabs
    transpose_cast<<<dim3(D / 32, D / 32), dim3(32, 8), 0, stream>>>(wo + (long)l * D * D, wT, D, D);
    gemm_bt<128, 64, 64, EPI_NONE, float><<<dim3(D / 64, S / 128, 2), 256, 0, stream>>>(
        ctx, (long)(D / 2), D, wT, (long)(D / 2), D, tmpf, (long)S * D, D, nullptr, D / 2, 1.f);
    ln_residual2<<<S, 256, 0, stream>>>(X, tmpf, tmpf + (long)S * D, bo + l * D,
                                        ln1g + l * D, ln1b + l * D, xb);

    // FFN (FFN1 at 128x128 -> 512 blocks = 2/CU exact, 2x MFMA per staged byte)
    transpose_cast<<<dim3(F / 32, D / 32), dim3(32, 8), 0, stream>>>(w1 + (long)l * D * F, wT, D, F);
    gemm_bt<128, 128, 64, EPI_BIAS_GELU_BF16, bf16><<<dim3(F / 128, S / 128, 1), 256, 0, stream>>>(
        xb, 0L, D, wT, 0L, D, hb, 0L, F, b1 + l * F, D, 1.f);
    transpose_cast<<<dim3(D / 32, F / 32), dim3(32, 8), 0, stream>>>(w2 + (long)l * F * D, wT, F, D);
    gemm_bt<128, 64, 64, EPI_NONE, float><<<dim3(D / 64, S / 128, 2), 256, 0, stream>>>(
        hb, (long)(F / 2), F, wT, (long)(F / 2), F, tmpf, (long)S * D, D, nullptr, F / 2, 1.f);
    ln_residual2<<<S, 256, 0, stream>>>(X, tmpf, tmpf + (long)S * D, b2 + l * D,
                                        ln2g + l * D, ln2b + l * D, xb);
  }
  copy_out<<<2048, 256, 0, stream>>>(X, (float*)d_out, S * D);
}

// Round 8
// 1002.487 us; speedup vs baseline: 1.1717x; 1.1717x over previous
//
#include <hip/hip_runtime.h>
#include <hip/hip_bf16.h>
#include <math.h>

typedef __hip_bfloat16 bf16;
typedef __attribute__((ext_vector_type(8))) short bf16x8;
typedef __attribute__((ext_vector_type(4))) short bf16x4;
typedef __attribute__((ext_vector_type(4))) float f32x4;

#define EPI_NONE 0
#define EPI_BIAS_BF16 1
#define EPI_BIAS_GELU_BF16 2

#define CLOG 0.18033688f   // 0.125 * log2(e) — attention scale folded into exp2

__device__ __forceinline__ void gload16(const void* g, void* l) {
  __builtin_amdgcn_global_load_lds((const __attribute__((address_space(1))) void*)g,
                                   (__attribute__((address_space(3))) void*)l, 16, 0, 0);
}

__device__ __forceinline__ float gelu_tanh(float x) {
  const float c = 0.7978845608028654f;
  float t = tanhf(c * (x + 0.044715f * x * x * x));
  return 0.5f * x * (1.0f + t);
}

__device__ __forceinline__ short bf16bits(float x) {
  bf16 h = __float2bfloat16(x);
  return *reinterpret_cast<const short*>(&h);
}

// C = A @ Bt^T (+bias, epilogue). A:[M][K] bf16 lda, Bt:[N][K] bf16 ldb.
// z: generic slab offsets (split-K). 256 thr = 4 waves, wave tile (BM/2)x(BN/2).
// global_load_lds width-16 staging; BK=64 halves barrier count vs BK=32.
template<int BM, int BN, int BK, int EPI, typename CT>
__global__ __launch_bounds__(256) void gemm_bt(
    const bf16* __restrict__ A, long sAz, int lda,
    const bf16* __restrict__ Bt, long sBz, int ldb,
    CT* __restrict__ C, long sCz, int ldc,
    const float* __restrict__ bias,
    int K, float scale)
{
  constexpr int WM = BM / 2, WN = BN / 2;
  constexpr int MI = WM / 16, NJ = WN / 16;
  constexpr int NA = (BM * BK * 2) / 4096;
  constexpr int NB = (BN * BK * 2) / 4096;
  constexpr int ROWB = BK * 2;          // bytes per LDS row
  __shared__ __align__(16) bf16 As[BM * BK];
  __shared__ __align__(16) bf16 Bs[BN * BK];
  const int t = threadIdx.x;
  const int lane = t & 63, w = t >> 6;
  const int wm = (w >> 1) * WM, wn = (w & 1) * WN;
  const int quad = lane >> 4, r16 = lane & 15;
  const long z = blockIdx.z;
  const bf16* Ab = A + z * sAz + (long)blockIdx.y * BM * lda;
  const bf16* Bb = Bt + z * sBz + (long)blockIdx.x * BN * ldb;

  f32x4 acc[MI][NJ];
  #pragma unroll
  for (int i = 0; i < MI; ++i)
    #pragma unroll
    for (int j = 0; j < NJ; ++j)
      acc[i][j] = (f32x4){0.f, 0.f, 0.f, 0.f};

  for (int k0 = 0; k0 < K; k0 += BK) {
    __syncthreads();
    #pragma unroll
    for (int s = 0; s < NA; ++s) {
      int Lb = s * 4096 + t * 16;
      int row = Lb / ROWB, colb = Lb % ROWB;
      gload16((const char*)Ab + (long)row * (lda * 2) + k0 * 2 + colb, (char*)As + Lb);
    }
    #pragma unroll
    for (int s = 0; s < NB; ++s) {
      int Lb = s * 4096 + t * 16;
      int row = Lb / ROWB, colb = Lb % ROWB;
      gload16((const char*)Bb + (long)row * (ldb * 2) + k0 * 2 + colb, (char*)Bs + Lb);
    }
    __syncthreads();   // vmcnt(0) drain before barrier (compiler-inserted)

    #pragma unroll
    for (int kk = 0; kk < BK / 32; ++kk) {
      bf16x8 af[MI], bfv[NJ];
      #pragma unroll
      for (int i = 0; i < MI; ++i)
        af[i] = *(const bf16x8*)&As[(wm + i * 16 + r16) * BK + kk * 32 + quad * 8];
      #pragma unroll
      for (int j = 0; j < NJ; ++j)
        bfv[j] = *(const bf16x8*)&Bs[(wn + j * 16 + r16) * BK + kk * 32 + quad * 8];
      #pragma unroll
      for (int i = 0; i < MI; ++i)
        #pragma unroll
        for (int j = 0; j < NJ; ++j)
          acc[i][j] = __builtin_amdgcn_mfma_f32_16x16x32_bf16(af[i], bfv[j], acc[i][j], 0, 0, 0);
    }
  }

  CT* Cb = C + z * sCz;
  #pragma unroll
  for (int i = 0; i < MI; ++i) {
    #pragma unroll
    for (int j = 0; j < NJ; ++j) {
      int col = blockIdx.x * BN + wn + j * 16 + r16;
      float bvv = 0.f;
      if constexpr (EPI == EPI_BIAS_BF16 || EPI == EPI_BIAS_GELU_BF16)
        bvv = bias[col];
      #pragma unroll
      for (int r = 0; r < 4; ++r) {
        long row = (long)blockIdx.y * BM + wm + i * 16 + quad * 4 + r;
        float val = acc[i][j][r] * scale + bvv;
        if constexpr (EPI == EPI_BIAS_GELU_BF16) val = gelu_tanh(val);
        if constexpr (sizeof(CT) == 2)
          Cb[row * (long)ldc + col] = __float2bfloat16(val);
        else
          Cb[row * (long)ldc + col] = val;
      }
    }
  }
}

// Key-split flash attention, 8-wave blocks: block = (128-row Q tile, head, split).
// The proven round-2 loop body per wave (LDS-staged K/V, one-tile-ahead register
// prefetch, 2 barriers/tile, swapped QK^T + lane-local softmax), but each staged
// 16 KB K/V tile now feeds 8 waves (128 Q rows) instead of 4 — staging bytes and
// barriers per Q-row halved. Each thread stages exactly one 16B chunk per array.
// Q fragments direct from global (verified r7). Grid (16,16,2)=512 -> 2 blocks/CU,
// 16 waves/CU (~50% occupancy); LDS 38.9 KB.
__global__ __launch_bounds__(512) void flash_attn(
    const bf16* __restrict__ qkv, const bf16* __restrict__ vT,
    float* __restrict__ Osp, float2* __restrict__ ml, int kts)
{
  constexpr int SEQ = 2048, LDP = 72, LDPP = 80;
  __shared__ __align__(16) bf16 Ks[64 * LDP];
  __shared__ __align__(16) bf16 VTs[64 * LDP];
  __shared__ __align__(16) bf16 Ps[128 * LDPP];

  const int t = threadIdx.x;           // 0..511
  const int lane = t & 63, w = t >> 6; // 8 waves
  const int quad = lane >> 4, r16 = lane & 15;
  const int wq0 = w * 16;              // wave's Q-row base within the 128-row tile
  const int s0 = blockIdx.x * 128;
  const int h = blockIdx.y;
  const int split = blockIdx.z;
  const int kt0 = split * kts, ktN = kt0 + kts;

  // Q fragments direct from global: row s0+wq0+r16, col h*64 + kk*32 + quad*8
  bf16x8 af_q[2];
  {
    const bf16* qp = qkv + (long)(s0 + wq0 + r16) * 3072 + h * 64 + quad * 8;
    af_q[0] = *(const bf16x8*)(qp);
    af_q[1] = *(const bf16x8*)(qp + 32);
  }

  // staging: thread t owns the 16B chunk at byte offset t*16 of each 8 KB tile
  const int Lb = t * 16;
  const int krow = Lb >> 7, kcolb = Lb & 127;
  const bf16* kp = qkv + 1024 + (long)h * 64 + (long)krow * 3072 + (kcolb >> 1);
  const bf16* vp = vT + (long)(h * 64 + krow) * SEQ + (kcolb >> 1);

  int4 rk = *(const int4*)(kp + (long)kt0 * 64 * 3072);
  int4 rv = *(const int4*)(vp + (long)kt0 * 64);

  f32x4 O[4];
  float m_s = -1e30f, l_s = 0.f;   // per-lane: running (m,l) of q-row r16 (exp2/C-scaled)
  #pragma unroll
  for (int jd = 0; jd < 4; ++jd) O[jd] = (f32x4){0.f, 0.f, 0.f, 0.f};

  for (int kt = kt0; kt < ktN; ++kt) {
    __syncthreads();
    *(int4*)((char*)Ks + (krow * LDP * 2) + kcolb) = rk;
    *(int4*)((char*)VTs + (krow * LDP * 2) + kcolb) = rv;
    __syncthreads();

    if (kt + 1 < ktN) {
      long k0n = (long)(kt + 1) * 64;
      rk = *(const int4*)(kp + k0n * 3072);
      rv = *(const int4*)(vp + k0n);
    }

    // S^T = K @ Q^T (raw; scale folded into exp2 constant).
    // sc[jb] reg r = S[qrow=r16][key = jb*16 + quad*4 + r]
    f32x4 sc[4];
    #pragma unroll
    for (int j = 0; j < 4; ++j) sc[j] = (f32x4){0.f, 0.f, 0.f, 0.f};
    #pragma unroll
    for (int kk = 0; kk < 2; ++kk) {
      bf16x8 bk_f[4];
      #pragma unroll
      for (int j = 0; j < 4; ++j)
        bk_f[j] = *(const bf16x8*)&Ks[(j * 16 + r16) * LDP + kk * 32 + quad * 8];
      #pragma unroll
      for (int j = 0; j < 4; ++j)
        sc[j] = __builtin_amdgcn_mfma_f32_16x16x32_bf16(bk_f[j], af_q[kk], sc[j], 0, 0, 0);
    }

    // lane-local online softmax for q-row r16: 16 in-lane keys + quad reduce
    float mj[4];
    #pragma unroll
    for (int j = 0; j < 4; ++j)
      mj[j] = fmaxf(fmaxf(sc[j][0], sc[j][1]), fmaxf(sc[j][2], sc[j][3]));
    float mx = fmaxf(fmaxf(mj[0], mj[1]), fmaxf(mj[2], mj[3]));
    mx = fmaxf(mx, __shfl_xor(mx, 16));
    mx = fmaxf(mx, __shfl_xor(mx, 32));
    float m_new = fmaxf(m_s, mx * CLOG);
    float alpha = exp2f(m_s - m_new);
    m_s = m_new;
    float p[4][4], sj[4];
    #pragma unroll
    for (int j = 0; j < 4; ++j) {
      #pragma unroll
      for (int r = 0; r < 4; ++r)
        p[j][r] = exp2f(fmaf(sc[j][r], CLOG, -m_new));
      sj[j] = (p[j][0] + p[j][1]) + (p[j][2] + p[j][3]);
    }
    float rs = (sj[0] + sj[1]) + (sj[2] + sj[3]);
    rs += __shfl_xor(rs, 16);
    rs += __shfl_xor(rs, 32);
    l_s = l_s * alpha + rs;

    // O rows are quad*4+r; their alpha lives at lane (*, r16'=quad*4+r)
    float ar[4];
    #pragma unroll
    for (int r = 0; r < 4; ++r)
      ar[r] = __shfl(alpha, quad * 20 + r);   // src = quad*16 + (quad*4+r)
    #pragma unroll
    for (int jd = 0; jd < 4; ++jd)
      #pragma unroll
      for (int r = 0; r < 4; ++r)
        O[jd][r] *= ar[r];

    // pack P row r16 -> LDS as 4x b64 (wave-private rows; same-wave DS ordering)
    {
      bf16* pr = &Ps[(wq0 + r16) * LDPP + quad * 4];
      #pragma unroll
      for (int j = 0; j < 4; ++j) {
        bf16x4 pk;
        #pragma unroll
        for (int r = 0; r < 4; ++r)
          pk[r] = bf16bits(p[j][r]);
        *(bf16x4*)(pr + j * 16) = pk;
      }
    }

    // O += P @ V via VT[d][key]
    #pragma unroll
    for (int kk = 0; kk < 2; ++kk) {
      bf16x8 af_p, bv_f[4];
      af_p = *(const bf16x8*)&Ps[(wq0 + r16) * LDPP + kk * 32 + quad * 8];
      #pragma unroll
      for (int jd = 0; jd < 4; ++jd)
        bv_f[jd] = *(const bf16x8*)&VTs[(jd * 16 + r16) * LDP + kk * 32 + quad * 8];
      #pragma unroll
      for (int jd = 0; jd < 4; ++jd)
        O[jd] = __builtin_amdgcn_mfma_f32_16x16x32_bf16(af_p, bv_f[jd], O[jd], 0, 0, 0);
    }
  }

  // epilogue: unnormalized fp32 O + (m,l)
  float* Ob = Osp + (long)split * SEQ * 1024;
  #pragma unroll
  for (int r = 0; r < 4; ++r) {
    long row = s0 + wq0 + quad * 4 + r;
    #pragma unroll
    for (int jd = 0; jd < 4; ++jd)
      Ob[row * 1024 + h * 64 + jd * 16 + r16] = O[jd][r];
  }
  if (quad == 0)
    ml[((long)(split * 16 + h)) * SEQ + (s0 + wq0 + r16)] = make_float2(m_s, l_s);
}

// merge nsplit key-splits -> ctx bf16
__global__ __launch_bounds__(256) void attn_combine(
    const float* __restrict__ Osp, const float2* __restrict__ ml,
    bf16* __restrict__ ctx, int nsplit)
{
  constexpr long SD = 2048L * 1024L;
  const int s = blockIdx.x;
  const int t = threadIdx.x;
  #pragma unroll
  for (int i = 0; i < 4; ++i) {
    int c = t + i * 256;
    int h = c >> 6;
    float mC = -1e30f;
    for (int sp = 0; sp < nsplit; ++sp)
      mC = fmaxf(mC, ml[(long)(sp * 16 + h) * 2048 + s].x);
    float denom = 0.f, num = 0.f;
    for (int sp = 0; sp < nsplit; ++sp) {
      float2 a = ml[(long)(sp * 16 + h) * 2048 + s];
      float wv = exp2f(a.x - mC);
      denom += a.y * wv;
      num += Osp[sp * SD + (long)s * 1024 + c] * wv;
    }
    ctx[(long)s * 1024 + c] = __float2bfloat16(num / denom);
  }
}

// fp32 weight [R][C] -> bf16 transposed [C][R]
__global__ __launch_bounds__(256) void transpose_cast(
    const float* __restrict__ in, bf16* __restrict__ out, int R, int C)
{
  __shared__ bf16 tile[32][33];
  const int tx = threadIdx.x, ty = threadIdx.y;
  const int r0 = blockIdx.y * 32, c0 = blockIdx.x * 32;
  #pragma unroll
  for (int d = 0; d < 32; d += 8)
    tile[ty + d][tx] = __float2bfloat16(in[(long)(r0 + ty + d) * C + c0 + tx]);
  __syncthreads();
  #pragma unroll
  for (int d = 0; d < 32; d += 8)
    out[(long)(c0 + ty + d) * R + r0 + tx] = tile[tx][ty + d];
}

// batched variant: z selects one of three same-shape fp32 [R][C] weights,
// output slabs out + z*R*C. Saves 2 kernel launches per layer for QKV.
__global__ __launch_bounds__(256) void transpose_cast3(
    const float* __restrict__ w0, const float* __restrict__ w1p,
    const float* __restrict__ w2p, bf16* __restrict__ out, int R, int C)
{
  __shared__ bf16 tile[32][33];
  const float* in = (blockIdx.z == 0) ? w0 : (blockIdx.z == 1) ? w1p : w2p;
  bf16* o = out + (long)blockIdx.z * R * C;
  const int tx = threadIdx.x, ty = threadIdx.y;
  const int r0 = blockIdx.y * 32, c0 = blockIdx.x * 32;
  #pragma unroll
  for (int d = 0; d < 32; d += 8)
    tile[ty + d][tx] = __float2bfloat16(in[(long)(r0 + ty + d) * C + c0 + tx]);
  __syncthreads();
  #pragma unroll
  for (int d = 0; d < 32; d += 8)
    o[(long)(c0 + ty + d) * R + r0 + tx] = tile[tx][ty + d];
}

// bf16 [R][C] (row stride ldin) -> bf16 transposed [C][R]
__global__ __launch_bounds__(256) void transpose_bf16(
    const bf16* __restrict__ in, bf16* __restrict__ out, int R, int C, int ldin)
{
  __shared__ bf16 tile[32][33];
  const int tx = threadIdx.x, ty = threadIdx.y;
  const int r0 = blockIdx.y * 32, c0 = blockIdx.x * 32;
  #pragma unroll
  for (int d = 0; d < 32; d += 8)
    tile[ty + d][tx] = in[(long)(r0 + ty + d) * ldin + c0 + tx];
  __syncthreads();
  #pragma unroll
  for (int d = 0; d < 32; d += 8)
    out[(long)(c0 + ty + d) * R + r0 + tx] = tile[tx][ty + d];
}

__device__ __forceinline__ float blk_sum(float v, float* sh) {
  #pragma unroll
  for (int o = 32; o > 0; o >>= 1) v += __shfl_down(v, o);
  __syncthreads();
  if ((threadIdx.x & 63) == 0) sh[threadIdx.x >> 6] = v;
  __syncthreads();
  return sh[0] + sh[1] + sh[2] + sh[3];
}

// X = LN(X + d0 + d1 + bias)*g + b, writes bf16 copy to xb.
__global__ __launch_bounds__(256) void ln_residual2(
    float* __restrict__ X, const float* __restrict__ d0, const float* __restrict__ d1,
    const float* __restrict__ bias,
    const float* __restrict__ g, const float* __restrict__ b,
    bf16* __restrict__ xb)
{
  __shared__ float sh[4];
  const int t = threadIdx.x;
  const long base = (long)blockIdx.x * 1024;
  float v[4]; float s = 0.f;
  #pragma unroll
  for (int i = 0; i < 4; ++i) {
    int c = t + i * 256;
    float val = X[base + c] + d0[base + c] + d1[base + c] + bias[c];
    v[i] = val; s += val;
  }
  s = blk_sum(s, sh);
  const float mu = s * (1.f / 1024.f);
  float s2 = 0.f;
  #pragma unroll
  for (int i = 0; i < 4; ++i) { float d = v[i] - mu; s2 += d * d; }
  s2 = blk_sum(s2, sh);
  const float rs = rsqrtf(s2 * (1.f / 1024.f) + 1e-5f);
  #pragma unroll
  for (int i = 0; i < 4; ++i) {
    int c = t + i * 256;
    float o = (v[i] - mu) * rs * g[c] + b[c];
    X[base + c] = o;
    xb[base + c] = __float2bfloat16(o);
  }
}

__global__ __launch_bounds__(256) void init_x(
    const float* __restrict__ xin, float* __restrict__ X, bf16* __restrict__ xb, int n)
{
  for (int i = blockIdx.x * 256 + threadIdx.x; i < n; i += gridDim.x * 256) {
    float v = xin[i];
    X[i] = v;
    xb[i] = __float2bfloat16(v);
  }
}

__global__ __launch_bounds__(256) void copy_out(
    const float* __restrict__ X, float* __restrict__ out, int n)
{
  for (int i = blockIdx.x * 256 + threadIdx.x; i < n; i += gridDim.x * 256)
    out[i] = X[i];
}

// bias3[l][j][c] = {bq,bk,bv}[l][c]
__global__ __launch_bounds__(256) void concat_bias(
    const float* __restrict__ bq, const float* __restrict__ bk,
    const float* __restrict__ bv, float* __restrict__ out, int n)
{
  for (int i = blockIdx.x * 256 + threadIdx.x; i < n; i += gridDim.x * 256) {
    int l = i / 3072, r = i % 3072;
    int j = r / 1024, c = r % 1024;
    const float* src = (j == 0) ? bq : (j == 1) ? bk : bv;
    out[i] = src[l * 1024 + c];
  }
}

extern "C" void kernel_launch(void* const* d_in, const int* in_sizes, int n_in,
                              void* d_out, int out_size, void* d_ws, size_t ws_size,
                              hipStream_t stream) {
  constexpr int S = 2048, D = 1024, F = 4096, L = 4;
  const float* xin = (const float*)d_in[0];
  const float* wq = (const float*)d_in[1];
  const float* bq = (const float*)d_in[2];
  const float* wk = (const float*)d_in[3];
  const float* bk = (const float*)d_in[4];
  const float* wv = (const float*)d_in[5];
  const float* bvp = (const float*)d_in[6];
  const float* wo = (const float*)d_in[7];
  const float* bo = (const float*)d_in[8];
  const float* w1 = (const float*)d_in[9];
  const float* b1 = (const float*)d_in[10];
  const float* w2 = (const float*)d_in[11];
  const float* b2 = (const float*)d_in[12];
  const float* ln1g = (const float*)d_in[13];
  const float* ln1b = (const float*)d_in[14];
  const float* ln2g = (const float*)d_in[15];
  const float* ln2b = (const float*)d_in[16];

  const int nsplit = 2;
  const int kts = 32 / nsplit;   // K-tiles (64 keys each) per split

  // workspace ~58 MB. tmpf doubles as flash O-split slabs; hb overlays qkv..ctx.
  char* p = (char*)d_ws;
  float* X    = (float*)p; p += (long)S * D * 4;            // 8 MB
  float* tmpf = (float*)p; p += (long)nsplit * S * D * 4;   // 16 MB (split-K / O-split slabs)
  bf16* xb    = (bf16*)p;  p += (long)S * D * 2;            // 4 MB
  bf16* qkv   = (bf16*)p;                                   // 12 MB
  bf16* hb    = (bf16*)p;  p += (long)S * 3 * D * 2;        // hb overlays qkv..ctx
  bf16* ctx   = (bf16*)p;  p += (long)S * D * 2;            // 4 MB
  bf16* vT    = (bf16*)p;  p += (long)S * D * 2;            // 4 MB  [H*64][S]
  bf16* wT    = (bf16*)p;  p += (long)F * D * 2;            // 8 MB
  float* bias3= (float*)p; p += (long)L * 3 * D * 4;        // 48 KB
  float2* ml  = (float2*)p; p += (long)nsplit * 16 * S * 8; // (m,l) per split/head/row

  init_x<<<2048, 256, 0, stream>>>(xin, X, xb, S * D);
  concat_bias<<<48, 256, 0, stream>>>(bq, bk, bvp, bias3, L * 3 * D);

  for (int l = 0; l < L; ++l) {
    // fused QKV: one batched transpose launch + balanced 128x64 GEMM (3 blocks/CU)
    transpose_cast3<<<dim3(D / 32, D / 32, 3), dim3(32, 8), 0, stream>>>(
        wq + (long)l * D * D, wk + (long)l * D * D, wv + (long)l * D * D, wT, D, D);
    gemm_bt<128, 64, 64, EPI_BIAS_BF16, bf16><<<dim3(3 * D / 64, S / 128, 1), 256, 0, stream>>>(
        xb, 0L, D, wT, 0L, D, qkv, 0L, 3 * D, bias3 + l * 3 * D, D, 1.f);

    // vT[h*64+d][s]
    transpose_bf16<<<dim3(D / 32, S / 32), dim3(32, 8), 0, stream>>>(qkv + 2 * D, vT, S, D, 3 * D);

    // key-split flash (8-wave, 128-row Q tiles) + combine
    flash_attn<<<dim3(S / 128, 16, nsplit), 512, 0, stream>>>(qkv, vT, tmpf, ml, kts);
    attn_combine<<<S, 256, 0, stream>>>(tmpf, ml, ctx, nsplit);

    // attn-out, split-K 2 -> fp32 slabs
    transpose_cast<<<dim3(D / 32, D / 32), dim3(32, 8), 0, stream>>>(wo + (long)l * D * D, wT, D, D);
    gemm_bt<128, 64, 64, EPI_NONE, float><<<dim3(D / 64, S / 128, 2), 256, 0, stream>>>(
        ctx, (long)(D / 2), D, wT, (long)(D / 2), D, tmpf, (long)S * D, D, nullptr, D / 2, 1.f);
    ln_residual2<<<S, 256, 0, stream>>>(X, tmpf, tmpf + (long)S * D, bo + l * D,
                                        ln1g + l * D, ln1b + l * D, xb);

    // FFN (both at 128x64: FFN1 1024 blocks = 4/CU, FFN2 split-K 2 -> 512 = 2/CU)
    transpose_cast<<<dim3(F / 32, D / 32), dim3(32, 8), 0, stream>>>(w1 + (long)l * D * F, wT, D, F);
    gemm_bt<128, 64, 64, EPI_BIAS_GELU_BF16, bf16><<<dim3(F / 64, S / 128, 1), 256, 0, stream>>>(
        xb, 0L, D, wT, 0L, D, hb, 0L, F, b1 + l * F, D, 1.f);
    transpose_cast<<<dim3(D / 32, F / 32), dim3(32, 8), 0, stream>>>(w2 + (long)l * F * D, wT, F, D);
    gemm_bt<128, 64, 64, EPI_NONE, float><<<dim3(D / 64, S / 128, 2), 256, 0, stream>>>(
        hb, (long)(F / 2), F, wT, (long)(F / 2), F, tmpf, (long)S * D, D, nullptr, F / 2, 1.f);
    ln_residual2<<<S, 256, 0, stream>>>(X, tmpf, tmpf + (long)S * D, b2 + l * D,
                                        ln2g + l * D, ln2b + l * D, xb);
  }
  copy_out<<<2048, 256, 0, stream>>>(X, (float*)d_out, S * D);
}